// Round 9
// baseline (85.874 us; speedup 1.0000x reference)
//
#include <hip/hip_runtime.h>
#include <math.h>

#define INDIM 10
#define DIM 32
#define LAYERS 4
#define MODES 17

// d_ws layout:
//   [0, 16384)        : wc f32 [4][32][32]
//   [16384, 27648)    : frag f16 [11][64][8]  (A-operand fragments, W^T form)
//   [27648, 28416)    : bias2 f32 [6][32]     (compact per-stage bias tables)
#define WS_FRAG_OFF 16384
#define WS_BIAS_OFF 27648

typedef _Float16 f16;
typedef _Float16 f16x8 __attribute__((ext_vector_type(8)));
typedef float f32x16 __attribute__((ext_vector_type(16)));
typedef unsigned u32x2 __attribute__((ext_vector_type(2)));

union BU { f16x8 v; unsigned u[4]; };
union CU { f32x16 v; float4 q[4]; };

// ---------------------------------------------------------------------------
// Fold rfft -> complex mode-mix -> irfft into a real 32x32 matrix per layer,
// added to proj_W.  Wc[l] = M_l + proj_W[l].  (verified round 1)
// ---------------------------------------------------------------------------
__global__ void fno_precompute(const float* __restrict__ wr,
                               const float* __restrict__ wi,
                               const float* __restrict__ projW,
                               float* __restrict__ wc) {
    const int l  = blockIdx.x;
    const int tx = threadIdx.x;
    const int j  = tx & 31;
    const int n  = tx >> 5;

    __shared__ float ct[32], st[32];
    if (tx < 32) {
        float ang = (2.0f * 3.14159265358979323846f / 32.0f) * (float)tx;
        ct[tx] = cosf(ang);
        st[tx] = sinf(ang);
    }
    __syncthreads();

    const float* lwr = wr + l * MODES * MODES;
    const float* lwi = wi + l * MODES * MODES;

    float acc = 0.0f;
    for (int o = 0; o < MODES; ++o) {
        float re = 0.0f, im = 0.0f;
        for (int m = 0; m < MODES; ++m) {
            int t = (m * n) & 31;
            float c = ct[t], s = st[t];
            float a = lwr[m * MODES + o];
            float b = lwi[m * MODES + o];
            re += c * a + s * b;
            im += c * b - s * a;
        }
        int t2 = (o * j) & 31;
        float f = (o == 0 || o == 16) ? 1.0f : 2.0f;
        acc += f * (re * ct[t2] - im * st[t2]);
    }
    acc *= (1.0f / 32.0f);
    wc[(l * DIM + n) * DIM + j] = acc + projW[(l * DIM + n) * DIM + j];
}

// ---------------------------------------------------------------------------
// Pack A-operand fragments (A = W^T: row=lane&31, k=8*(lane>>5)+e) and the
// compact per-stage bias tables bias2[6][32] (stem, 4 layers, head).
// frag idx: 0..7 = layer l*2+kc; 8 = stem; 9,10 = head k-chunks.
// ---------------------------------------------------------------------------
__global__ void fno_pack(const float* __restrict__ wc,
                         const float* __restrict__ stemW,
                         const float* __restrict__ headW,
                         const float* __restrict__ stemB,
                         const float* __restrict__ projB,
                         const float* __restrict__ headB,
                         f16* __restrict__ frag,
                         float* __restrict__ bias2) {
    const int ln = threadIdx.x;  // 64
    const int c  = ln & 31;
    const int G  = ln >> 5;

#pragma unroll
    for (int l = 0; l < LAYERS; ++l)
#pragma unroll
        for (int kc = 0; kc < 2; ++kc)
#pragma unroll
            for (int e = 0; e < 8; ++e) {
                int k = 16 * kc + 8 * G + e;
                frag[((l * 2 + kc) * 64 + ln) * 8 + e] = (f16)wc[(l * DIM + k) * DIM + c];
            }
#pragma unroll
    for (int e = 0; e < 8; ++e) {
        int k = 8 * G + e;
        frag[(8 * 64 + ln) * 8 + e] = (f16)(k < INDIM ? stemW[k * DIM + c] : 0.0f);
    }
#pragma unroll
    for (int kc = 0; kc < 2; ++kc)
#pragma unroll
        for (int e = 0; e < 8; ++e) {
            int k = 16 * kc + 8 * G + e;
            frag[((9 + kc) * 64 + ln) * 8 + e] =
                (f16)(c < INDIM ? headW[k * INDIM + c] : 0.0f);
        }

    if (ln < 32) {
#pragma unroll
        for (int f = 0; f < 6; ++f) {
            float v;
            if (f == 0)      v = stemB[ln];
            else if (f <= 4) v = projB[(f - 1) * DIM + ln];
            else             v = (ln < INDIM) ? headB[ln] : 0.0f;
            bias2[f * 32 + ln] = v;
        }
    }
}

__device__ __forceinline__ float silu_f(float v) {
    return v * __builtin_amdgcn_rcpf(1.0f + __expf(-v));
}

__device__ __forceinline__ unsigned pk2(float a, float b) {
    auto h2 = __builtin_amdgcn_cvt_pkrtz(a, b);   // v_cvt_pkrtz_f16_f32
    return __builtin_bit_cast(unsigned, h2);
}

// Compiler-modeled lane<32 <-> lane>=32 exchange (round-8-verified correct).
__device__ __forceinline__ void pswap(unsigned& a, unsigned& b) {
#if __has_builtin(__builtin_amdgcn_permlane32_swap)
    u32x2 r = __builtin_amdgcn_permlane32_swap(a, b, false, false);
    a = r[0];
    b = r[1];
#else
    asm("v_permlane32_swap_b32 %0, %1" : "+v"(a), "+v"(b));
    __builtin_amdgcn_sched_barrier(0);
#endif
}

// D (f32x16) -> next-layer B-fragments, entirely in registers.
template <bool SILU>
__device__ __forceinline__ void pack_exchange(const f32x16& D, BU& b0, BU& b1) {
    float s[16];
#pragma unroll
    for (int r = 0; r < 16; ++r) s[r] = SILU ? silu_f(D[r]) : D[r];
    unsigned q0 = pk2(s[0],  s[1]);
    unsigned q1 = pk2(s[2],  s[3]);
    unsigned q2 = pk2(s[4],  s[5]);
    unsigned q3 = pk2(s[6],  s[7]);
    unsigned q4 = pk2(s[8],  s[9]);
    unsigned q5 = pk2(s[10], s[11]);
    unsigned q6 = pk2(s[12], s[13]);
    unsigned q7 = pk2(s[14], s[15]);
    pswap(q0, q2);
    pswap(q1, q3);
    pswap(q4, q6);
    pswap(q5, q7);
    b0.u[0] = q0; b0.u[1] = q1; b0.u[2] = q2; b0.u[3] = q3;
    b1.u[0] = q4; b1.u[1] = q5; b1.u[2] = q6; b1.u[3] = q7;
}

// C-operand bias fragment from the 768B LDS table (half-wave broadcast reads).
__device__ __forceinline__ f32x16 ld_bias(const float* sbias, int stage, int G) {
    CU c;
#pragma unroll
    for (int rq = 0; rq < 4; ++rq)
        c.q[rq] = *(const float4*)&sbias[stage * 32 + rq * 8 + G * 4];
    return c.v;
}

// Raw x row loads (float2 regs) -- issue early, pack at use so HBM/L2/L3
// latency hides under the previous tile-pair's compute.
struct XR { float2 p0, p1, p2, p3; };

template <bool GUARD>
__device__ __forceinline__ XR load_x_raw(const float* __restrict__ x, long rb,
                                         int c, int G, int nrows) {
    XR r = {};
    const long row = rb + c;
    const bool ok = !GUARD || (row < nrows);
    const float* xp = x + row * INDIM;
    if (ok) {
        if (G == 0) {
            r.p0 = *(const float2*)(xp + 0);
            r.p1 = *(const float2*)(xp + 2);
            r.p2 = *(const float2*)(xp + 4);
            r.p3 = *(const float2*)(xp + 6);
        } else {
            r.p0 = *(const float2*)(xp + 8);
        }
    }
    return r;
}

__device__ __forceinline__ BU pack_x(const XR& r, int G) {
    BU b;
    if (G == 0) {
        b.u[0] = pk2(r.p0.x, r.p0.y);
        b.u[1] = pk2(r.p1.x, r.p1.y);
        b.u[2] = pk2(r.p2.x, r.p2.y);
        b.u[3] = pk2(r.p3.x, r.p3.y);
    } else {
        b.u[0] = pk2(r.p0.x, r.p0.y);
        b.u[1] = 0; b.u[2] = 0; b.u[3] = 0;
    }
    return b;
}

template <bool GUARD>
__device__ __forceinline__ void store_o(float* __restrict__ out, long rb,
                                        int c, int G, int nrows, const f32x16& Dh) {
    const long r = rb + c;
    if (!GUARD || r < nrows) {
        float* op = out + r * INDIM;
        if (G == 0) {
            *(float2*)(op + 0) = make_float2(Dh[0], Dh[1]);  // f0,f1
            *(float2*)(op + 2) = make_float2(Dh[2], Dh[3]);  // f2,f3
            *(float2*)(op + 8) = make_float2(Dh[4], Dh[5]);  // f8,f9
        } else {
            *(float2*)(op + 4) = make_float2(Dh[0], Dh[1]);  // f4,f5
            *(float2*)(op + 6) = make_float2(Dh[2], Dh[3]);  // f6,f7
        }
    }
}

// One dual-chain tile-pair: stem -> 4 layers -> head -> store (64 rows).
template <bool GUARD>
__device__ __forceinline__ void run_pair(const f16x8* wa, f16x8 as, f16x8 ah0,
                                         f16x8 ah1, const float* sbias,
                                         BU bxA, BU bxB,
                                         float* __restrict__ out,
                                         long rbA, long rbB,
                                         int c, int G, int nrows) {
    const f32x16 csv = ld_bias(sbias, 0, G);
    f32x16 DA = __builtin_amdgcn_mfma_f32_32x32x16_f16(as, bxA.v, csv, 0, 0, 0);
    f32x16 DB = __builtin_amdgcn_mfma_f32_32x32x16_f16(as, bxB.v, csv, 0, 0, 0);

    BU a0, a1, b0, b1;
    pack_exchange<false>(DA, a0, a1);
    pack_exchange<false>(DB, b0, b1);

#pragma unroll
    for (int l = 0; l < LAYERS; ++l) {
        const f32x16 clv = ld_bias(sbias, 1 + l, G);
        f32x16 tA = __builtin_amdgcn_mfma_f32_32x32x16_f16(wa[2 * l], a0.v, clv, 0, 0, 0);
        f32x16 tB = __builtin_amdgcn_mfma_f32_32x32x16_f16(wa[2 * l], b0.v, clv, 0, 0, 0);
        tA = __builtin_amdgcn_mfma_f32_32x32x16_f16(wa[2 * l + 1], a1.v, tA, 0, 0, 0);
        tB = __builtin_amdgcn_mfma_f32_32x32x16_f16(wa[2 * l + 1], b1.v, tB, 0, 0, 0);
        pack_exchange<true>(tA, a0, a1);
        pack_exchange<true>(tB, b0, b1);
    }

    const f32x16 hv = ld_bias(sbias, 5, G);
    f32x16 HA = __builtin_amdgcn_mfma_f32_32x32x16_f16(ah0, a0.v, hv, 0, 0, 0);
    f32x16 HB = __builtin_amdgcn_mfma_f32_32x32x16_f16(ah0, b0.v, hv, 0, 0, 0);
    HA = __builtin_amdgcn_mfma_f32_32x32x16_f16(ah1, a1.v, HA, 0, 0, 0);
    HB = __builtin_amdgcn_mfma_f32_32x32x16_f16(ah1, b1.v, HB, 0, 0, 0);

    store_o<GUARD>(out, rbA, c, G, nrows, HA);
    store_o<GUARD>(out, rbB, c, G, nrows, HB);
}

// ---------------------------------------------------------------------------
// Main: transposed 32x32 MFMA pipeline. Each wave runs TWO dual-chain
// tile-pairs (128 rows); the second pair's x-loads are issued at wave start
// so their latency hides under the first pair's compute. Weight/bias
// preamble amortized 2x; block count halved. GUARD=false when nrows % 512
// == 0 (drops all bounds-check cndmasks).
// ---------------------------------------------------------------------------
template <bool GUARD>
__global__ __launch_bounds__(256, 3) void fno_main(
    const float* __restrict__ x,
    const f16*  __restrict__ fragbuf,   // [11][64][8] f16
    const float* __restrict__ bias2,    // [6][32] f32
    float* __restrict__ out,
    int nrows) {

    __shared__ __align__(16) float sbias[6 * 32];
    if (threadIdx.x < 6 * 32) sbias[threadIdx.x] = bias2[threadIdx.x];
    __syncthreads();

    const int tid = threadIdx.x;
    const int w   = tid >> 6;
    const int ln  = tid & 63;
    const int c   = ln & 31;
    const int G   = ln >> 5;

    const f16x8* fb = (const f16x8*)fragbuf;
    f16x8 wa[2 * LAYERS];
#pragma unroll
    for (int f = 0; f < 2 * LAYERS; ++f) wa[f] = fb[f * 64 + ln];
    const f16x8 as  = fb[8 * 64 + ln];
    const f16x8 ah0 = fb[9 * 64 + ln];
    const f16x8 ah1 = fb[10 * 64 + ln];

    const long base = (long)blockIdx.x * 512 + (long)w * 128;

    // Issue ALL x loads up-front (FIFO: pair-0 data arrives first).
    XR xA0 = load_x_raw<GUARD>(x, base +  0, c, G, nrows);
    XR xB0 = load_x_raw<GUARD>(x, base + 32, c, G, nrows);
    XR xA1 = load_x_raw<GUARD>(x, base + 64, c, G, nrows);
    XR xB1 = load_x_raw<GUARD>(x, base + 96, c, G, nrows);

    // ---- pair 0 ----
    BU bA0 = pack_x(xA0, G);
    BU bB0 = pack_x(xB0, G);
    run_pair<GUARD>(wa, as, ah0, ah1, sbias, bA0, bB0, out,
                    base + 0, base + 32, c, G, nrows);

    // ---- pair 1 (loads long in flight) ----
    BU bA1 = pack_x(xA1, G);
    BU bB1 = pack_x(xB1, G);
    run_pair<GUARD>(wa, as, ah0, ah1, sbias, bA1, bB1, out,
                    base + 64, base + 96, c, G, nrows);
}

extern "C" void kernel_launch(void* const* d_in, const int* in_sizes, int n_in,
                              void* d_out, int out_size, void* d_ws, size_t ws_size,
                              hipStream_t stream) {
    const float* x      = (const float*)d_in[0];
    const float* stemW  = (const float*)d_in[1];
    const float* stemB  = (const float*)d_in[2];
    const float* fno_wr = (const float*)d_in[3];
    const float* fno_wi = (const float*)d_in[4];
    const float* projW  = (const float*)d_in[5];
    const float* projB  = (const float*)d_in[6];
    const float* headW  = (const float*)d_in[7];
    const float* headB  = (const float*)d_in[8];
    float* out = (float*)d_out;

    float* wcb   = (float*)d_ws;
    f16*   frag  = (f16*)((char*)d_ws + WS_FRAG_OFF);
    float* bias2 = (float*)((char*)d_ws + WS_BIAS_OFF);

    const int nrows = in_sizes[0] / INDIM;

    fno_precompute<<<LAYERS, 1024, 0, stream>>>(fno_wr, fno_wi, projW, wcb);
    fno_pack<<<1, 64, 0, stream>>>(wcb, stemW, headW, stemB, projB, headB, frag, bias2);

    const int rows_per_block = 512;   // 4 waves x 2 pairs x 2 chains x 32 rows
    const int nblk = (nrows + rows_per_block - 1) / rows_per_block;
    if (nrows % rows_per_block == 0)
        fno_main<false><<<nblk, 256, 0, stream>>>(x, frag, bias2, out, nrows);
    else
        fno_main<true><<<nblk, 256, 0, stream>>>(x, frag, bias2, out, nrows);
}

// Round 10
// 67.551 us; speedup vs baseline: 1.2713x; 1.2713x over previous
//
#include <hip/hip_runtime.h>
#include <math.h>

#define INDIM 10
#define DIM 32
#define LAYERS 4
#define MODES 17

// d_ws layout:
//   [0, 16384)        : wc f32 [4][32][32]
//   [16384, 27648)    : frag f16 [11][64][8]  (A-operand fragments, W^T form)
//   [27648, 28416)    : bias2 f32 [6][32]     (compact per-stage bias tables)
#define WS_FRAG_OFF 16384
#define WS_BIAS_OFF 27648

typedef _Float16 f16;
typedef _Float16 f16x8 __attribute__((ext_vector_type(8)));
typedef float f32x16 __attribute__((ext_vector_type(16)));
typedef unsigned u32x2 __attribute__((ext_vector_type(2)));

union BU { f16x8 v; unsigned u[4]; };
union CU { f32x16 v; float4 q[4]; };

// ---------------------------------------------------------------------------
// Fold rfft -> complex mode-mix -> irfft into a real 32x32 matrix per layer,
// added to proj_W.  Wc[l] = M_l + proj_W[l].  (verified round 1)
// ---------------------------------------------------------------------------
__global__ void fno_precompute(const float* __restrict__ wr,
                               const float* __restrict__ wi,
                               const float* __restrict__ projW,
                               float* __restrict__ wc) {
    const int l  = blockIdx.x;
    const int tx = threadIdx.x;
    const int j  = tx & 31;
    const int n  = tx >> 5;

    __shared__ float ct[32], st[32];
    if (tx < 32) {
        float ang = (2.0f * 3.14159265358979323846f / 32.0f) * (float)tx;
        ct[tx] = cosf(ang);
        st[tx] = sinf(ang);
    }
    __syncthreads();

    const float* lwr = wr + l * MODES * MODES;
    const float* lwi = wi + l * MODES * MODES;

    float acc = 0.0f;
    for (int o = 0; o < MODES; ++o) {
        float re = 0.0f, im = 0.0f;
        for (int m = 0; m < MODES; ++m) {
            int t = (m * n) & 31;
            float c = ct[t], s = st[t];
            float a = lwr[m * MODES + o];
            float b = lwi[m * MODES + o];
            re += c * a + s * b;
            im += c * b - s * a;
        }
        int t2 = (o * j) & 31;
        float f = (o == 0 || o == 16) ? 1.0f : 2.0f;
        acc += f * (re * ct[t2] - im * st[t2]);
    }
    acc *= (1.0f / 32.0f);
    wc[(l * DIM + n) * DIM + j] = acc + projW[(l * DIM + n) * DIM + j];
}

// ---------------------------------------------------------------------------
// Pack A-operand fragments (A = W^T: row=lane&31, k=8*(lane>>5)+e) and the
// compact per-stage bias tables bias2[6][32] (stem, 4 layers, head).
// frag idx: 0..7 = layer l*2+kc; 8 = stem; 9,10 = head k-chunks.
// ---------------------------------------------------------------------------
__global__ void fno_pack(const float* __restrict__ wc,
                         const float* __restrict__ stemW,
                         const float* __restrict__ headW,
                         const float* __restrict__ stemB,
                         const float* __restrict__ projB,
                         const float* __restrict__ headB,
                         f16* __restrict__ frag,
                         float* __restrict__ bias2) {
    const int ln = threadIdx.x;  // 64
    const int c  = ln & 31;
    const int G  = ln >> 5;

#pragma unroll
    for (int l = 0; l < LAYERS; ++l)
#pragma unroll
        for (int kc = 0; kc < 2; ++kc)
#pragma unroll
            for (int e = 0; e < 8; ++e) {
                int k = 16 * kc + 8 * G + e;
                frag[((l * 2 + kc) * 64 + ln) * 8 + e] = (f16)wc[(l * DIM + k) * DIM + c];
            }
#pragma unroll
    for (int e = 0; e < 8; ++e) {
        int k = 8 * G + e;
        frag[(8 * 64 + ln) * 8 + e] = (f16)(k < INDIM ? stemW[k * DIM + c] : 0.0f);
    }
#pragma unroll
    for (int kc = 0; kc < 2; ++kc)
#pragma unroll
        for (int e = 0; e < 8; ++e) {
            int k = 16 * kc + 8 * G + e;
            frag[((9 + kc) * 64 + ln) * 8 + e] =
                (f16)(c < INDIM ? headW[k * INDIM + c] : 0.0f);
        }

    if (ln < 32) {
#pragma unroll
        for (int f = 0; f < 6; ++f) {
            float v;
            if (f == 0)      v = stemB[ln];
            else if (f <= 4) v = projB[(f - 1) * DIM + ln];
            else             v = (ln < INDIM) ? headB[ln] : 0.0f;
            bias2[f * 32 + ln] = v;
        }
    }
}

__device__ __forceinline__ float silu_f(float v) {
    return v * __builtin_amdgcn_rcpf(1.0f + __expf(-v));
}

__device__ __forceinline__ unsigned pk2(float a, float b) {
    auto h2 = __builtin_amdgcn_cvt_pkrtz(a, b);   // v_cvt_pkrtz_f16_f32
    return __builtin_bit_cast(unsigned, h2);
}

// Compiler-modeled lane<32 <-> lane>=32 exchange (round-8-verified correct).
__device__ __forceinline__ void pswap(unsigned& a, unsigned& b) {
#if __has_builtin(__builtin_amdgcn_permlane32_swap)
    u32x2 r = __builtin_amdgcn_permlane32_swap(a, b, false, false);
    a = r[0];
    b = r[1];
#else
    asm("v_permlane32_swap_b32 %0, %1" : "+v"(a), "+v"(b));
    __builtin_amdgcn_sched_barrier(0);
#endif
}

// D (f32x16) -> next-layer B-fragments, entirely in registers.
template <bool SILU>
__device__ __forceinline__ void pack_exchange(const f32x16& D, BU& b0, BU& b1) {
    float s[16];
#pragma unroll
    for (int r = 0; r < 16; ++r) s[r] = SILU ? silu_f(D[r]) : D[r];
    unsigned q0 = pk2(s[0],  s[1]);
    unsigned q1 = pk2(s[2],  s[3]);
    unsigned q2 = pk2(s[4],  s[5]);
    unsigned q3 = pk2(s[6],  s[7]);
    unsigned q4 = pk2(s[8],  s[9]);
    unsigned q5 = pk2(s[10], s[11]);
    unsigned q6 = pk2(s[12], s[13]);
    unsigned q7 = pk2(s[14], s[15]);
    pswap(q0, q2);
    pswap(q1, q3);
    pswap(q4, q6);
    pswap(q5, q7);
    b0.u[0] = q0; b0.u[1] = q1; b0.u[2] = q2; b0.u[3] = q3;
    b1.u[0] = q4; b1.u[1] = q5; b1.u[2] = q6; b1.u[3] = q7;
}

// C-operand bias fragment from the 768B LDS table (half-wave broadcast reads).
__device__ __forceinline__ f32x16 ld_bias(const float* sbias, int stage, int G) {
    CU c;
#pragma unroll
    for (int rq = 0; rq < 4; ++rq)
        c.q[rq] = *(const float4*)&sbias[stage * 32 + rq * 8 + G * 4];
    return c.v;
}

template <bool GUARD>
__device__ __forceinline__ BU load_x(const float* __restrict__ x, long rb,
                                     int c, int G, int nrows) {
    BU b;
    b.u[0] = 0; b.u[1] = 0; b.u[2] = 0; b.u[3] = 0;
    const long r = rb + c;
    if (!GUARD || r < nrows) {
        const float* xp = x + r * INDIM;
        if (G == 0) {
            float2 p0 = *(const float2*)(xp + 0);
            float2 p1 = *(const float2*)(xp + 2);
            float2 p2 = *(const float2*)(xp + 4);
            float2 p3 = *(const float2*)(xp + 6);
            b.u[0] = pk2(p0.x, p0.y);
            b.u[1] = pk2(p1.x, p1.y);
            b.u[2] = pk2(p2.x, p2.y);
            b.u[3] = pk2(p3.x, p3.y);
        } else {
            float2 p4 = *(const float2*)(xp + 8);
            b.u[0] = pk2(p4.x, p4.y);
        }
    }
    return b;
}

template <bool GUARD>
__device__ __forceinline__ void store_o(float* __restrict__ out, long rb,
                                        int c, int G, int nrows, const f32x16& Dh) {
    const long r = rb + c;
    if (!GUARD || r < nrows) {
        float* op = out + r * INDIM;
        if (G == 0) {
            *(float2*)(op + 0) = make_float2(Dh[0], Dh[1]);  // f0,f1
            *(float2*)(op + 2) = make_float2(Dh[2], Dh[3]);  // f2,f3
            *(float2*)(op + 8) = make_float2(Dh[4], Dh[5]);  // f8,f9
        } else {
            *(float2*)(op + 4) = make_float2(Dh[0], Dh[1]);  // f4,f5
            *(float2*)(op + 6) = make_float2(Dh[2], Dh[3]);  // f6,f7
        }
    }
}

// ---------------------------------------------------------------------------
// Main: transposed 32x32 MFMA pipeline, DUAL independent 32-row chains per
// wave interleaved stage-by-stage (round-8-verified structure: one tile-pair
// per wave, stores clustered at wave end -> partial row-writes merge in L2,
// zero write amplification).  This round's single change: launch_bounds
// (256,5) forces allocation <= ~102 unified regs so ~5 waves/SIMD are
// resident (was 2.9 at (256,3)) to fill the trans/MFMA latency stalls.
// ---------------------------------------------------------------------------
template <bool GUARD>
__global__ __launch_bounds__(256, 5) void fno_main(
    const float* __restrict__ x,
    const f16*  __restrict__ fragbuf,   // [11][64][8] f16
    const float* __restrict__ bias2,    // [6][32] f32
    float* __restrict__ out,
    int nrows) {

    __shared__ __align__(16) float sbias[6 * 32];
    if (threadIdx.x < 6 * 32) sbias[threadIdx.x] = bias2[threadIdx.x];
    __syncthreads();

    const int tid = threadIdx.x;
    const int w   = tid >> 6;
    const int ln  = tid & 63;
    const int c   = ln & 31;
    const int G   = ln >> 5;

    const f16x8* fb = (const f16x8*)fragbuf;
    f16x8 wa[2 * LAYERS];
#pragma unroll
    for (int f = 0; f < 2 * LAYERS; ++f) wa[f] = fb[f * 64 + ln];
    const f16x8 as  = fb[8 * 64 + ln];
    const f16x8 ah0 = fb[9 * 64 + ln];
    const f16x8 ah1 = fb[10 * 64 + ln];

    const long rbA = (long)blockIdx.x * 256 + (long)w * 64;
    const long rbB = rbA + 32;

    // ---- stem: shared C-frag, two independent MFMAs ----
    BU bxA = load_x<GUARD>(x, rbA, c, G, nrows);
    BU bxB = load_x<GUARD>(x, rbB, c, G, nrows);
    const f32x16 csv = ld_bias(sbias, 0, G);
    f32x16 DA = __builtin_amdgcn_mfma_f32_32x32x16_f16(as, bxA.v, csv, 0, 0, 0);
    f32x16 DB = __builtin_amdgcn_mfma_f32_32x32x16_f16(as, bxB.v, csv, 0, 0, 0);

    BU a0, a1, b0, b1;
    pack_exchange<false>(DA, a0, a1);
    pack_exchange<false>(DB, b0, b1);

    // ---- 4 fused layers, dual chains ----
#pragma unroll
    for (int l = 0; l < LAYERS; ++l) {
        const f32x16 clv = ld_bias(sbias, 1 + l, G);
        f32x16 tA = __builtin_amdgcn_mfma_f32_32x32x16_f16(wa[2 * l], a0.v, clv, 0, 0, 0);
        f32x16 tB = __builtin_amdgcn_mfma_f32_32x32x16_f16(wa[2 * l], b0.v, clv, 0, 0, 0);
        tA = __builtin_amdgcn_mfma_f32_32x32x16_f16(wa[2 * l + 1], a1.v, tA, 0, 0, 0);
        tB = __builtin_amdgcn_mfma_f32_32x32x16_f16(wa[2 * l + 1], b1.v, tB, 0, 0, 0);
        pack_exchange<true>(tA, a0, a1);
        pack_exchange<true>(tB, b0, b1);
    }

    // ---- head, dual chains ----
    const f32x16 hv = ld_bias(sbias, 5, G);
    f32x16 HA = __builtin_amdgcn_mfma_f32_32x32x16_f16(ah0, a0.v, hv, 0, 0, 0);
    f32x16 HB = __builtin_amdgcn_mfma_f32_32x32x16_f16(ah0, b0.v, hv, 0, 0, 0);
    HA = __builtin_amdgcn_mfma_f32_32x32x16_f16(ah1, a1.v, HA, 0, 0, 0);
    HB = __builtin_amdgcn_mfma_f32_32x32x16_f16(ah1, b1.v, HB, 0, 0, 0);

    store_o<GUARD>(out, rbA, c, G, nrows, HA);
    store_o<GUARD>(out, rbB, c, G, nrows, HB);
}

extern "C" void kernel_launch(void* const* d_in, const int* in_sizes, int n_in,
                              void* d_out, int out_size, void* d_ws, size_t ws_size,
                              hipStream_t stream) {
    const float* x      = (const float*)d_in[0];
    const float* stemW  = (const float*)d_in[1];
    const float* stemB  = (const float*)d_in[2];
    const float* fno_wr = (const float*)d_in[3];
    const float* fno_wi = (const float*)d_in[4];
    const float* projW  = (const float*)d_in[5];
    const float* projB  = (const float*)d_in[6];
    const float* headW  = (const float*)d_in[7];
    const float* headB  = (const float*)d_in[8];
    float* out = (float*)d_out;

    float* wcb   = (float*)d_ws;
    f16*   frag  = (f16*)((char*)d_ws + WS_FRAG_OFF);
    float* bias2 = (float*)((char*)d_ws + WS_BIAS_OFF);

    const int nrows = in_sizes[0] / INDIM;

    fno_precompute<<<LAYERS, 1024, 0, stream>>>(fno_wr, fno_wi, projW, wcb);
    fno_pack<<<1, 64, 0, stream>>>(wcb, stemW, headW, stemB, projB, headB, frag, bias2);

    const int rows_per_block = 256;   // 4 waves x 2 chains x 32 rows
    const int nblk = (nrows + rows_per_block - 1) / rows_per_block;
    if (nrows % rows_per_block == 0)
        fno_main<false><<<nblk, 256, 0, stream>>>(x, frag, bias2, out, nrows);
    else
        fno_main<true><<<nblk, 256, 0, stream>>>(x, frag, bias2, out, nrows);
}

// Round 11
// 64.452 us; speedup vs baseline: 1.3324x; 1.0481x over previous
//
#include <hip/hip_runtime.h>
#include <math.h>

#define INDIM 10
#define DIM 32
#define LAYERS 4
#define MODES 17

#define LOG2E 1.4426950408889634f
#define LN2   0.6931471805599453f

// d_ws layout:
//   [0, 16384)        : wc f32 [4][32][32]
//   [16384, 27648)    : frag f16 [11][64][8]  (A-operand fragments, W^T form)
//   [27648, 28416)    : bias2 f32 [6][32]     (compact per-stage bias tables)
#define WS_FRAG_OFF 16384
#define WS_BIAS_OFF 27648

typedef _Float16 f16;
typedef _Float16 f16x8 __attribute__((ext_vector_type(8)));
typedef float f32x16 __attribute__((ext_vector_type(16)));
typedef unsigned u32x2 __attribute__((ext_vector_type(2)));

union BU { f16x8 v; unsigned u[4]; };
union CU { f32x16 v; float4 q[4]; };

// ---------------------------------------------------------------------------
// Fold rfft -> complex mode-mix -> irfft into a real 32x32 matrix per layer,
// added to proj_W.  Wc[l] = M_l + proj_W[l].  (verified round 1)
// ---------------------------------------------------------------------------
__global__ void fno_precompute(const float* __restrict__ wr,
                               const float* __restrict__ wi,
                               const float* __restrict__ projW,
                               float* __restrict__ wc) {
    const int l  = blockIdx.x;
    const int tx = threadIdx.x;
    const int j  = tx & 31;
    const int n  = tx >> 5;

    __shared__ float ct[32], st[32];
    if (tx < 32) {
        float ang = (2.0f * 3.14159265358979323846f / 32.0f) * (float)tx;
        ct[tx] = cosf(ang);
        st[tx] = sinf(ang);
    }
    __syncthreads();

    const float* lwr = wr + l * MODES * MODES;
    const float* lwi = wi + l * MODES * MODES;

    float acc = 0.0f;
    for (int o = 0; o < MODES; ++o) {
        float re = 0.0f, im = 0.0f;
        for (int m = 0; m < MODES; ++m) {
            int t = (m * n) & 31;
            float c = ct[t], s = st[t];
            float a = lwr[m * MODES + o];
            float b = lwi[m * MODES + o];
            re += c * a + s * b;
            im += c * b - s * a;
        }
        int t2 = (o * j) & 31;
        float f = (o == 0 || o == 16) ? 1.0f : 2.0f;
        acc += f * (re * ct[t2] - im * st[t2]);
    }
    acc *= (1.0f / 32.0f);
    wc[(l * DIM + n) * DIM + j] = acc + projW[(l * DIM + n) * DIM + j];
}

// ---------------------------------------------------------------------------
// Pack A-operand fragments (A = W^T: row=lane&31, k=8*(lane>>5)+e) and the
// compact per-stage bias tables bias2[6][32] (stem, 4 layers, head).
// frag idx: 0..7 = layer l*2+kc; 8 = stem; 9,10 = head k-chunks.
//
// log2e FOLDING (kernel computes silu'(d) = d * rcp(1 + exp2(-d))):
// Let h'_l = D'_l * sigma(D'_l/log2e).  Requiring D'_l = log2e*(W_l h + b_l):
//   layer 0: input h0 is true-scale -> Wc[0] *= LOG2E, b *= LOG2E
//   layer l>=1: input h'_{l-1} = h_true*LOG2E -> Wc[l] UNCHANGED, b *= LOG2E
//   head: input h'_3 -> headW *= LN2 (headB unchanged)
// ---------------------------------------------------------------------------
__global__ void fno_pack(const float* __restrict__ wc,
                         const float* __restrict__ stemW,
                         const float* __restrict__ headW,
                         const float* __restrict__ stemB,
                         const float* __restrict__ projB,
                         const float* __restrict__ headB,
                         f16* __restrict__ frag,
                         float* __restrict__ bias2) {
    const int ln = threadIdx.x;  // 64
    const int c  = ln & 31;
    const int G  = ln >> 5;

#pragma unroll
    for (int l = 0; l < LAYERS; ++l) {
        const float wscale = (l == 0) ? LOG2E : 1.0f;
#pragma unroll
        for (int kc = 0; kc < 2; ++kc)
#pragma unroll
            for (int e = 0; e < 8; ++e) {
                int k = 16 * kc + 8 * G + e;
                frag[((l * 2 + kc) * 64 + ln) * 8 + e] =
                    (f16)(wscale * wc[(l * DIM + k) * DIM + c]);
            }
    }
#pragma unroll
    for (int e = 0; e < 8; ++e) {
        int k = 8 * G + e;
        frag[(8 * 64 + ln) * 8 + e] = (f16)(k < INDIM ? stemW[k * DIM + c] : 0.0f);
    }
#pragma unroll
    for (int kc = 0; kc < 2; ++kc)
#pragma unroll
        for (int e = 0; e < 8; ++e) {
            int k = 16 * kc + 8 * G + e;
            frag[((9 + kc) * 64 + ln) * 8 + e] =
                (f16)(c < INDIM ? LN2 * headW[k * INDIM + c] : 0.0f);
        }

    if (ln < 32) {
#pragma unroll
        for (int f = 0; f < 6; ++f) {
            float v;
            if (f == 0)      v = stemB[ln];
            else if (f <= 4) v = LOG2E * projB[(f - 1) * DIM + ln];
            else             v = (ln < INDIM) ? headB[ln] : 0.0f;
            bias2[f * 32 + ln] = v;
        }
    }
}

__device__ __forceinline__ float exp2_fast(float x) {
#if __has_builtin(__builtin_amdgcn_exp2f)
    return __builtin_amdgcn_exp2f(x);
#else
    return exp2f(x);
#endif
}

__device__ __forceinline__ unsigned pk2(float a, float b) {
    auto h2 = __builtin_amdgcn_cvt_pkrtz(a, b);   // v_cvt_pkrtz_f16_f32
    return __builtin_bit_cast(unsigned, h2);
}

// Compiler-modeled lane<32 <-> lane>=32 exchange (round-8-verified correct).
__device__ __forceinline__ void pswap(unsigned& a, unsigned& b) {
#if __has_builtin(__builtin_amdgcn_permlane32_swap)
    u32x2 r = __builtin_amdgcn_permlane32_swap(a, b, false, false);
    a = r[0];
    b = r[1];
#else
    asm("v_permlane32_swap_b32 %0, %1" : "+v"(a), "+v"(b));
    __builtin_amdgcn_sched_barrier(0);
#endif
}

// Fused BOTH-chain D -> next-layer B-fragments, stage-major for trans-pipe
// pipelining: all exp2, then all add, then all rcp, then all mul -- 31
// independent ops between any dependent pair, so the quarter-rate trans ops
// issue back-to-back and other waves' main-VALU fills underneath.
template <bool SILU>
__device__ __forceinline__ void pack_exchange_dual(const f32x16& DA, const f32x16& DB,
                                                   BU& a0, BU& a1, BU& b0, BU& b1) {
    float sA[16], sB[16];
    if (SILU) {
        float uA[16], uB[16];
#pragma unroll
        for (int r = 0; r < 16; ++r) uA[r] = exp2_fast(-DA[r]);
#pragma unroll
        for (int r = 0; r < 16; ++r) uB[r] = exp2_fast(-DB[r]);
#pragma unroll
        for (int r = 0; r < 16; ++r) uA[r] = 1.0f + uA[r];
#pragma unroll
        for (int r = 0; r < 16; ++r) uB[r] = 1.0f + uB[r];
#pragma unroll
        for (int r = 0; r < 16; ++r) uA[r] = __builtin_amdgcn_rcpf(uA[r]);
#pragma unroll
        for (int r = 0; r < 16; ++r) uB[r] = __builtin_amdgcn_rcpf(uB[r]);
#pragma unroll
        for (int r = 0; r < 16; ++r) sA[r] = DA[r] * uA[r];
#pragma unroll
        for (int r = 0; r < 16; ++r) sB[r] = DB[r] * uB[r];
    } else {
#pragma unroll
        for (int r = 0; r < 16; ++r) { sA[r] = DA[r]; sB[r] = DB[r]; }
    }

    unsigned qa0 = pk2(sA[0],  sA[1]);
    unsigned qa1 = pk2(sA[2],  sA[3]);
    unsigned qa2 = pk2(sA[4],  sA[5]);
    unsigned qa3 = pk2(sA[6],  sA[7]);
    unsigned qa4 = pk2(sA[8],  sA[9]);
    unsigned qa5 = pk2(sA[10], sA[11]);
    unsigned qa6 = pk2(sA[12], sA[13]);
    unsigned qa7 = pk2(sA[14], sA[15]);
    unsigned qb0 = pk2(sB[0],  sB[1]);
    unsigned qb1 = pk2(sB[2],  sB[3]);
    unsigned qb2 = pk2(sB[4],  sB[5]);
    unsigned qb3 = pk2(sB[6],  sB[7]);
    unsigned qb4 = pk2(sB[8],  sB[9]);
    unsigned qb5 = pk2(sB[10], sB[11]);
    unsigned qb6 = pk2(sB[12], sB[13]);
    unsigned qb7 = pk2(sB[14], sB[15]);
    pswap(qa0, qa2); pswap(qa1, qa3); pswap(qa4, qa6); pswap(qa5, qa7);
    pswap(qb0, qb2); pswap(qb1, qb3); pswap(qb4, qb6); pswap(qb5, qb7);
    a0.u[0] = qa0; a0.u[1] = qa1; a0.u[2] = qa2; a0.u[3] = qa3;
    a1.u[0] = qa4; a1.u[1] = qa5; a1.u[2] = qa6; a1.u[3] = qa7;
    b0.u[0] = qb0; b0.u[1] = qb1; b0.u[2] = qb2; b0.u[3] = qb3;
    b1.u[0] = qb4; b1.u[1] = qb5; b1.u[2] = qb6; b1.u[3] = qb7;
}

// C-operand bias fragment from the 768B LDS table (half-wave broadcast reads).
__device__ __forceinline__ f32x16 ld_bias(const float* sbias, int stage, int G) {
    CU c;
#pragma unroll
    for (int rq = 0; rq < 4; ++rq)
        c.q[rq] = *(const float4*)&sbias[stage * 32 + rq * 8 + G * 4];
    return c.v;
}

template <bool GUARD>
__device__ __forceinline__ BU load_x(const float* __restrict__ x, long rb,
                                     int c, int G, int nrows) {
    BU b;
    b.u[0] = 0; b.u[1] = 0; b.u[2] = 0; b.u[3] = 0;
    const long r = rb + c;
    if (!GUARD || r < nrows) {
        const float* xp = x + r * INDIM;
        if (G == 0) {
            float2 p0 = *(const float2*)(xp + 0);
            float2 p1 = *(const float2*)(xp + 2);
            float2 p2 = *(const float2*)(xp + 4);
            float2 p3 = *(const float2*)(xp + 6);
            b.u[0] = pk2(p0.x, p0.y);
            b.u[1] = pk2(p1.x, p1.y);
            b.u[2] = pk2(p2.x, p2.y);
            b.u[3] = pk2(p3.x, p3.y);
        } else {
            float2 p4 = *(const float2*)(xp + 8);
            b.u[0] = pk2(p4.x, p4.y);
        }
    }
    return b;
}

template <bool GUARD>
__device__ __forceinline__ void store_o(float* __restrict__ out, long rb,
                                        int c, int G, int nrows, const f32x16& Dh) {
    const long r = rb + c;
    if (!GUARD || r < nrows) {
        float* op = out + r * INDIM;
        if (G == 0) {
            *(float2*)(op + 0) = make_float2(Dh[0], Dh[1]);  // f0,f1
            *(float2*)(op + 2) = make_float2(Dh[2], Dh[3]);  // f2,f3
            *(float2*)(op + 8) = make_float2(Dh[4], Dh[5]);  // f8,f9
        } else {
            *(float2*)(op + 4) = make_float2(Dh[0], Dh[1]);  // f4,f5
            *(float2*)(op + 6) = make_float2(Dh[2], Dh[3]);  // f6,f7
        }
    }
}

// ---------------------------------------------------------------------------
// Main: transposed 32x32 MFMA pipeline, dual 32-row chains per wave
// (round-8-verified structure), with stage-major fused silu across both
// chains and log2e folded into the weights.  launch_bounds (256,3) gives
// the wide interleave ~170 regs of headroom.
// ---------------------------------------------------------------------------
template <bool GUARD>
__global__ __launch_bounds__(256, 3) void fno_main(
    const float* __restrict__ x,
    const f16*  __restrict__ fragbuf,   // [11][64][8] f16
    const float* __restrict__ bias2,    // [6][32] f32
    float* __restrict__ out,
    int nrows) {

    __shared__ __align__(16) float sbias[6 * 32];
    if (threadIdx.x < 6 * 32) sbias[threadIdx.x] = bias2[threadIdx.x];
    __syncthreads();

    const int tid = threadIdx.x;
    const int w   = tid >> 6;
    const int ln  = tid & 63;
    const int c   = ln & 31;
    const int G   = ln >> 5;

    const f16x8* fb = (const f16x8*)fragbuf;
    f16x8 wa[2 * LAYERS];
#pragma unroll
    for (int f = 0; f < 2 * LAYERS; ++f) wa[f] = fb[f * 64 + ln];
    const f16x8 as  = fb[8 * 64 + ln];
    const f16x8 ah0 = fb[9 * 64 + ln];
    const f16x8 ah1 = fb[10 * 64 + ln];

    const long rbA = (long)blockIdx.x * 256 + (long)w * 64;
    const long rbB = rbA + 32;

    // ---- stem: shared C-frag, two independent MFMAs ----
    BU bxA = load_x<GUARD>(x, rbA, c, G, nrows);
    BU bxB = load_x<GUARD>(x, rbB, c, G, nrows);
    const f32x16 csv = ld_bias(sbias, 0, G);
    f32x16 DA = __builtin_amdgcn_mfma_f32_32x32x16_f16(as, bxA.v, csv, 0, 0, 0);
    f32x16 DB = __builtin_amdgcn_mfma_f32_32x32x16_f16(as, bxB.v, csv, 0, 0, 0);

    BU a0, a1, b0, b1;
    pack_exchange_dual<false>(DA, DB, a0, a1, b0, b1);

    // ---- 4 fused layers, dual chains ----
#pragma unroll
    for (int l = 0; l < LAYERS; ++l) {
        const f32x16 clv = ld_bias(sbias, 1 + l, G);
        f32x16 tA = __builtin_amdgcn_mfma_f32_32x32x16_f16(wa[2 * l], a0.v, clv, 0, 0, 0);
        f32x16 tB = __builtin_amdgcn_mfma_f32_32x32x16_f16(wa[2 * l], b0.v, clv, 0, 0, 0);
        tA = __builtin_amdgcn_mfma_f32_32x32x16_f16(wa[2 * l + 1], a1.v, tA, 0, 0, 0);
        tB = __builtin_amdgcn_mfma_f32_32x32x16_f16(wa[2 * l + 1], b1.v, tB, 0, 0, 0);
        pack_exchange_dual<true>(tA, tB, a0, a1, b0, b1);
    }

    // ---- head, dual chains ----
    const f32x16 hv = ld_bias(sbias, 5, G);
    f32x16 HA = __builtin_amdgcn_mfma_f32_32x32x16_f16(ah0, a0.v, hv, 0, 0, 0);
    f32x16 HB = __builtin_amdgcn_mfma_f32_32x32x16_f16(ah0, b0.v, hv, 0, 0, 0);
    HA = __builtin_amdgcn_mfma_f32_32x32x16_f16(ah1, a1.v, HA, 0, 0, 0);
    HB = __builtin_amdgcn_mfma_f32_32x32x16_f16(ah1, b1.v, HB, 0, 0, 0);

    store_o<GUARD>(out, rbA, c, G, nrows, HA);
    store_o<GUARD>(out, rbB, c, G, nrows, HB);
}

extern "C" void kernel_launch(void* const* d_in, const int* in_sizes, int n_in,
                              void* d_out, int out_size, void* d_ws, size_t ws_size,
                              hipStream_t stream) {
    const float* x      = (const float*)d_in[0];
    const float* stemW  = (const float*)d_in[1];
    const float* stemB  = (const float*)d_in[2];
    const float* fno_wr = (const float*)d_in[3];
    const float* fno_wi = (const float*)d_in[4];
    const float* projW  = (const float*)d_in[5];
    const float* projB  = (const float*)d_in[6];
    const float* headW  = (const float*)d_in[7];
    const float* headB  = (const float*)d_in[8];
    float* out = (float*)d_out;

    float* wcb   = (float*)d_ws;
    f16*   frag  = (f16*)((char*)d_ws + WS_FRAG_OFF);
    float* bias2 = (float*)((char*)d_ws + WS_BIAS_OFF);

    const int nrows = in_sizes[0] / INDIM;

    fno_precompute<<<LAYERS, 1024, 0, stream>>>(fno_wr, fno_wi, projW, wcb);
    fno_pack<<<1, 64, 0, stream>>>(wcb, stemW, headW, stemB, projB, headB, frag, bias2);

    const int rows_per_block = 256;   // 4 waves x 2 chains x 32 rows
    const int nblk = (nrows + rows_per_block - 1) / rows_per_block;
    if (nrows % rows_per_block == 0)
        fno_main<false><<<nblk, 256, 0, stream>>>(x, frag, bias2, out, nrows);
    else
        fno_main<true><<<nblk, 256, 0, stream>>>(x, frag, bias2, out, nrows);
}

// Round 13
// 57.982 us; speedup vs baseline: 1.4810x; 1.1116x over previous
//
#include <hip/hip_runtime.h>
#include <math.h>

#define INDIM 10
#define DIM 32
#define LAYERS 4
#define MODES 17

#define LOG2E 1.4426950408889634f
#define LN2   0.6931471805599453f

// d_ws layout:
//   [0, 11264)        : frag f16 [11][64][8]  (A-operand fragments, W^T form)
//   [11264, 12032)    : bias2 f32 [6][32]     (compact per-stage bias tables)
#define WS_FRAG_OFF 0
#define WS_BIAS_OFF 11264

typedef _Float16 f16;
typedef _Float16 f16x8 __attribute__((ext_vector_type(8)));
typedef float f32x16 __attribute__((ext_vector_type(16)));
typedef unsigned u32x2 __attribute__((ext_vector_type(2)));

union BU { f16x8 v; unsigned u[4]; };
union CU { f32x16 v; float4 q[4]; };

// ---------------------------------------------------------------------------
// FUSED prep: fold rfft -> complex mode-mix -> irfft into the real 32x32
// Wc[l] = M_l + proj_W[l] (verified round 1) and write the f16 A-operand
// fragments DIRECTLY (each thread's wc element maps to exactly one frag
// element).  Block 0 additionally packs stem/head fragments and the bias
// tables.  One launch replaces the old precompute+pack pair.
//
// frag layout (A = W^T: row=lane&31, k=8*(lane>>5)+e within 16-chunk kc):
//   frag[((l*2+kc)*64 + ln)*8 + e] = wscale * wc[l][k][c],
//   k = n = 16*kc + 8*G + e, c = j, ln = G*32 + j.
// log2e folding (round-11-verified): Wc[0]*=LOG2E, projB*=LOG2E, headW*=LN2.
// ---------------------------------------------------------------------------
__global__ void fno_prep(const float* __restrict__ wr,
                         const float* __restrict__ wi,
                         const float* __restrict__ projW,
                         const float* __restrict__ stemW,
                         const float* __restrict__ headW,
                         const float* __restrict__ stemB,
                         const float* __restrict__ projB,
                         const float* __restrict__ headB,
                         f16* __restrict__ frag,
                         float* __restrict__ bias2) {
    const int l  = blockIdx.x;
    const int tx = threadIdx.x;
    const int j  = tx & 31;   // output position n' (= frag column c)
    const int n  = tx >> 5;   // input position n  (= frag k)

    __shared__ float ct[32], st[32];
    if (tx < 32) {
        float ang = (2.0f * 3.14159265358979323846f / 32.0f) * (float)tx;
        ct[tx] = cosf(ang);
        st[tx] = sinf(ang);
    }
    __syncthreads();

    const float* lwr = wr + l * MODES * MODES;
    const float* lwi = wi + l * MODES * MODES;

    float acc = 0.0f;
    for (int o = 0; o < MODES; ++o) {
        float re = 0.0f, im = 0.0f;
        for (int m = 0; m < MODES; ++m) {
            int t = (m * n) & 31;
            float c = ct[t], s = st[t];
            float a = lwr[m * MODES + o];
            float b = lwi[m * MODES + o];
            re += c * a + s * b;
            im += c * b - s * a;
        }
        int t2 = (o * j) & 31;
        float f = (o == 0 || o == 16) ? 1.0f : 2.0f;
        acc += f * (re * ct[t2] - im * st[t2]);
    }
    acc = acc * (1.0f / 32.0f) + projW[(l * DIM + n) * DIM + j];

    const float wscale = (l == 0) ? LOG2E : 1.0f;
    const int kc = n >> 4;
    const int G  = (n >> 3) & 1;
    const int e  = n & 7;
    const int ln = G * 32 + j;
    frag[((l * 2 + kc) * 64 + ln) * 8 + e] = (f16)(wscale * acc);

    // ---- block 0 extras: stem/head fragments + bias tables ----
    if (l == 0) {
        if (tx < 64) {
            const int lnn = tx;
            const int c2  = lnn & 31;
            const int G2  = lnn >> 5;
#pragma unroll
            for (int ee = 0; ee < 8; ++ee) {
                int k = 8 * G2 + ee;
                frag[(8 * 64 + lnn) * 8 + ee] =
                    (f16)(k < INDIM ? stemW[k * DIM + c2] : 0.0f);
            }
#pragma unroll
            for (int kcc = 0; kcc < 2; ++kcc)
#pragma unroll
                for (int ee = 0; ee < 8; ++ee) {
                    int k = 16 * kcc + 8 * G2 + ee;
                    frag[((9 + kcc) * 64 + lnn) * 8 + ee] =
                        (f16)(c2 < INDIM ? LN2 * headW[k * INDIM + c2] : 0.0f);
                }
        }
        if (tx < 32) {
#pragma unroll
            for (int f = 0; f < 6; ++f) {
                float v;
                if (f == 0)      v = stemB[tx];
                else if (f <= 4) v = LOG2E * projB[(f - 1) * DIM + tx];
                else             v = (tx < INDIM) ? headB[tx] : 0.0f;
                bias2[f * 32 + tx] = v;
            }
        }
    }
}

__device__ __forceinline__ float exp2_fast(float x) {
#if __has_builtin(__builtin_amdgcn_exp2f)
    return __builtin_amdgcn_exp2f(x);
#else
    return exp2f(x);
#endif
}

__device__ __forceinline__ unsigned pk2(float a, float b) {
    auto h2 = __builtin_amdgcn_cvt_pkrtz(a, b);   // v_cvt_pkrtz_f16_f32
    return __builtin_bit_cast(unsigned, h2);
}

// Compiler-modeled lane<32 <-> lane>=32 exchange (round-8-verified correct).
__device__ __forceinline__ void pswap(unsigned& a, unsigned& b) {
#if __has_builtin(__builtin_amdgcn_permlane32_swap)
    u32x2 r = __builtin_amdgcn_permlane32_swap(a, b, false, false);
    a = r[0];
    b = r[1];
#else
    asm("v_permlane32_swap_b32 %0, %1" : "+v"(a), "+v"(b));
    __builtin_amdgcn_sched_barrier(0);
#endif
}

// Fused BOTH-chain D -> next-layer B-fragments, stage-major (round-11).
template <bool SILU>
__device__ __forceinline__ void pack_exchange_dual(const f32x16& DA, const f32x16& DB,
                                                   BU& a0, BU& a1, BU& b0, BU& b1) {
    float sA[16], sB[16];
    if (SILU) {
        float uA[16], uB[16];
#pragma unroll
        for (int r = 0; r < 16; ++r) uA[r] = exp2_fast(-DA[r]);
#pragma unroll
        for (int r = 0; r < 16; ++r) uB[r] = exp2_fast(-DB[r]);
#pragma unroll
        for (int r = 0; r < 16; ++r) uA[r] = 1.0f + uA[r];
#pragma unroll
        for (int r = 0; r < 16; ++r) uB[r] = 1.0f + uB[r];
#pragma unroll
        for (int r = 0; r < 16; ++r) uA[r] = __builtin_amdgcn_rcpf(uA[r]);
#pragma unroll
        for (int r = 0; r < 16; ++r) uB[r] = __builtin_amdgcn_rcpf(uB[r]);
#pragma unroll
        for (int r = 0; r < 16; ++r) sA[r] = DA[r] * uA[r];
#pragma unroll
        for (int r = 0; r < 16; ++r) sB[r] = DB[r] * uB[r];
    } else {
#pragma unroll
        for (int r = 0; r < 16; ++r) { sA[r] = DA[r]; sB[r] = DB[r]; }
    }

    unsigned qa0 = pk2(sA[0],  sA[1]);
    unsigned qa1 = pk2(sA[2],  sA[3]);
    unsigned qa2 = pk2(sA[4],  sA[5]);
    unsigned qa3 = pk2(sA[6],  sA[7]);
    unsigned qa4 = pk2(sA[8],  sA[9]);
    unsigned qa5 = pk2(sA[10], sA[11]);
    unsigned qa6 = pk2(sA[12], sA[13]);
    unsigned qa7 = pk2(sA[14], sA[15]);
    unsigned qb0 = pk2(sB[0],  sB[1]);
    unsigned qb1 = pk2(sB[2],  sB[3]);
    unsigned qb2 = pk2(sB[4],  sB[5]);
    unsigned qb3 = pk2(sB[6],  sB[7]);
    unsigned qb4 = pk2(sB[8],  sB[9]);
    unsigned qb5 = pk2(sB[10], sB[11]);
    unsigned qb6 = pk2(sB[12], sB[13]);
    unsigned qb7 = pk2(sB[14], sB[15]);
    pswap(qa0, qa2); pswap(qa1, qa3); pswap(qa4, qa6); pswap(qa5, qa7);
    pswap(qb0, qb2); pswap(qb1, qb3); pswap(qb4, qb6); pswap(qb5, qb7);
    a0.u[0] = qa0; a0.u[1] = qa1; a0.u[2] = qa2; a0.u[3] = qa3;
    a1.u[0] = qa4; a1.u[1] = qa5; a1.u[2] = qa6; a1.u[3] = qa7;
    b0.u[0] = qb0; b0.u[1] = qb1; b0.u[2] = qb2; b0.u[3] = qb3;
    b1.u[0] = qb4; b1.u[1] = qb5; b1.u[2] = qb6; b1.u[3] = qb7;
}

// C-operand bias fragment from the 768B LDS table (half-wave broadcast reads).
__device__ __forceinline__ f32x16 ld_bias(const float* sbias, int stage, int G) {
    CU c;
#pragma unroll
    for (int rq = 0; rq < 4; ++rq)
        c.q[rq] = *(const float4*)&sbias[stage * 32 + rq * 8 + G * 4];
    return c.v;
}

template <bool GUARD>
__device__ __forceinline__ BU load_x(const float* __restrict__ x, long rb,
                                     int c, int G, int nrows) {
    BU b;
    b.u[0] = 0; b.u[1] = 0; b.u[2] = 0; b.u[3] = 0;
    const long r = rb + c;
    if (!GUARD || r < nrows) {
        const float* xp = x + r * INDIM;
        if (G == 0) {
            float2 p0 = *(const float2*)(xp + 0);
            float2 p1 = *(const float2*)(xp + 2);
            float2 p2 = *(const float2*)(xp + 4);
            float2 p3 = *(const float2*)(xp + 6);
            b.u[0] = pk2(p0.x, p0.y);
            b.u[1] = pk2(p1.x, p1.y);
            b.u[2] = pk2(p2.x, p2.y);
            b.u[3] = pk2(p3.x, p3.y);
        } else {
            float2 p4 = *(const float2*)(xp + 8);
            b.u[0] = pk2(p4.x, p4.y);
        }
    }
    return b;
}

template <bool GUARD>
__device__ __forceinline__ void store_o(float* __restrict__ out, long rb,
                                        int c, int G, int nrows, const f32x16& Dh) {
    const long r = rb + c;
    if (!GUARD || r < nrows) {
        float* op = out + r * INDIM;
        if (G == 0) {
            *(float2*)(op + 0) = make_float2(Dh[0], Dh[1]);  // f0,f1
            *(float2*)(op + 2) = make_float2(Dh[2], Dh[3]);  // f2,f3
            *(float2*)(op + 8) = make_float2(Dh[4], Dh[5]);  // f8,f9
        } else {
            *(float2*)(op + 4) = make_float2(Dh[0], Dh[1]);  // f4,f5
            *(float2*)(op + 6) = make_float2(Dh[2], Dh[3]);  // f6,f7
        }
    }
}

// ---------------------------------------------------------------------------
// Main: transposed 32x32 MFMA pipeline, dual 32-row chains per wave,
// stage-major fused silu, log2e folded into weights (all verified).
// NEW: depth-1 bias prefetch -- the NEXT stage's 4 ds_read_b128 issue right
// after the current stage's MFMAs, so LDS latency hides under the silu VALU
// phase instead of heading each stage's dependency chain.
// ---------------------------------------------------------------------------
template <bool GUARD>
__global__ __launch_bounds__(256, 3) void fno_main(
    const float* __restrict__ x,
    const f16*  __restrict__ fragbuf,   // [11][64][8] f16
    const float* __restrict__ bias2,    // [6][32] f32
    float* __restrict__ out,
    int nrows) {

    __shared__ __align__(16) float sbias[6 * 32];
    if (threadIdx.x < 6 * 32) sbias[threadIdx.x] = bias2[threadIdx.x];
    __syncthreads();

    const int tid = threadIdx.x;
    const int w   = tid >> 6;
    const int ln  = tid & 63;
    const int c   = ln & 31;
    const int G   = ln >> 5;

    const f16x8* fb = (const f16x8*)fragbuf;
    f16x8 wa[2 * LAYERS];
#pragma unroll
    for (int f = 0; f < 2 * LAYERS; ++f) wa[f] = fb[f * 64 + ln];
    const f16x8 as  = fb[8 * 64 + ln];
    const f16x8 ah0 = fb[9 * 64 + ln];
    const f16x8 ah1 = fb[10 * 64 + ln];

    const long rbA = (long)blockIdx.x * 256 + (long)w * 64;
    const long rbB = rbA + 32;

    // ---- stem ----
    BU bxA = load_x<GUARD>(x, rbA, c, G, nrows);
    BU bxB = load_x<GUARD>(x, rbB, c, G, nrows);
    f32x16 cb = ld_bias(sbias, 0, G);                 // stem bias
    f32x16 DA = __builtin_amdgcn_mfma_f32_32x32x16_f16(as, bxA.v, cb, 0, 0, 0);
    f32x16 DB = __builtin_amdgcn_mfma_f32_32x32x16_f16(as, bxB.v, cb, 0, 0, 0);
    cb = ld_bias(sbias, 1, G);                        // prefetch layer-0 bias

    BU a0, a1, b0, b1;
    pack_exchange_dual<false>(DA, DB, a0, a1, b0, b1);

    // ---- 4 fused layers, dual chains, bias prefetched one stage ahead ----
#pragma unroll
    for (int l = 0; l < LAYERS; ++l) {
        f32x16 tA = __builtin_amdgcn_mfma_f32_32x32x16_f16(wa[2 * l], a0.v, cb, 0, 0, 0);
        f32x16 tB = __builtin_amdgcn_mfma_f32_32x32x16_f16(wa[2 * l], b0.v, cb, 0, 0, 0);
        tA = __builtin_amdgcn_mfma_f32_32x32x16_f16(wa[2 * l + 1], a1.v, tA, 0, 0, 0);
        tB = __builtin_amdgcn_mfma_f32_32x32x16_f16(wa[2 * l + 1], b1.v, tB, 0, 0, 0);
        cb = ld_bias(sbias, (l < LAYERS - 1) ? (2 + l) : 5, G);  // next stage
        pack_exchange_dual<true>(tA, tB, a0, a1, b0, b1);
    }

    // ---- head (cb now holds head bias) ----
    f32x16 HA = __builtin_amdgcn_mfma_f32_32x32x16_f16(ah0, a0.v, cb, 0, 0, 0);
    f32x16 HB = __builtin_amdgcn_mfma_f32_32x32x16_f16(ah0, b0.v, cb, 0, 0, 0);
    HA = __builtin_amdgcn_mfma_f32_32x32x16_f16(ah1, a1.v, HA, 0, 0, 0);
    HB = __builtin_amdgcn_mfma_f32_32x32x16_f16(ah1, b1.v, HB, 0, 0, 0);

    store_o<GUARD>(out, rbA, c, G, nrows, HA);
    store_o<GUARD>(out, rbB, c, G, nrows, HB);
}

extern "C" void kernel_launch(void* const* d_in, const int* in_sizes, int n_in,
                              void* d_out, int out_size, void* d_ws, size_t ws_size,
                              hipStream_t stream) {
    const float* x      = (const float*)d_in[0];
    const float* stemW  = (const float*)d_in[1];
    const float* stemB  = (const float*)d_in[2];
    const float* fno_wr = (const float*)d_in[3];
    const float* fno_wi = (const float*)d_in[4];
    const float* projW  = (const float*)d_in[5];
    const float* projB  = (const float*)d_in[6];
    const float* headW  = (const float*)d_in[7];
    const float* headB  = (const float*)d_in[8];
    float* out = (float*)d_out;

    f16*   frag  = (f16*)((char*)d_ws + WS_FRAG_OFF);
    float* bias2 = (float*)((char*)d_ws + WS_BIAS_OFF);

    const int nrows = in_sizes[0] / INDIM;

    fno_prep<<<LAYERS, 1024, 0, stream>>>(fno_wr, fno_wi, projW, stemW, headW,
                                          stemB, projB, headB, frag, bias2);

    const int rows_per_block = 256;   // 4 waves x 2 chains x 32 rows
    const int nblk = (nrows + rows_per_block - 1) / rows_per_block;
    if (nrows % rows_per_block == 0)
        fno_main<false><<<nblk, 256, 0, stream>>>(x, frag, bias2, out, nrows);
    else
        fno_main<true><<<nblk, 256, 0, stream>>>(x, frag, bias2, out, nrows);
}